// Round 5
// baseline (4819.088 us; speedup 1.0000x reference)
//
#include <hip/hip_runtime.h>
#include <hip/hip_bf16.h>
#include <hip/hip_cooperative_groups.h>

namespace cg = cooperative_groups;

// Problem constants (KoopmanKernelSeq2Seq)
#define M_  512
#define L_  16
#define O_  32
#define D_  64
#define B_  16
#define ML  8192          // M_*L_
#define SLOT (B_*ML)      // 131072 elements per scan slot

typedef __attribute__((ext_vector_type(8))) short short8;
typedef __attribute__((ext_vector_type(4))) float f32x4;

static constexpr float GAMMA = 1.0f / 128.0f;          // 1/(2*D)
static constexpr float SCALE = 0.0441941738241592f;    // 512^-0.5

__device__ __forceinline__ float sqdiff4(const float4& x, const float4& y) {
    float dx = x.x - y.x, dy = x.y - y.y, dz = x.z - y.z, dw = x.w - y.w;
    return dx*dx + dy*dy + dz*dz + dw*dw;
}

__device__ __forceinline__ unsigned short f2bf(float x) {   // RNE f32->bf16
    unsigned u = __float_as_uint(x);
    u = (u + 0x7FFFu + ((u >> 16) & 1u)) >> 16;
    return (unsigned short)u;
}

// ---- out0: RBF(nys_X, inps), dual write f32 + bf16 ----
__global__ __launch_bounds__(256) void k_out0_dual(const float* __restrict__ inps,
                                                   const float* __restrict__ X,
                                                   float* __restrict__ S0,
                                                   unsigned short* __restrict__ C0) {
    int idx = blockIdx.x * 256 + threadIdx.x;          // B*M*L = 131072
    int l = idx & (L_ - 1);
    int m = (idx >> 4) & (M_ - 1);
    int b = idx >> 13;
    const float* xr = X + m * D_;
    const float* yr = inps + (b * L_ + l) * D_;
    float d2 = 0.f;
#pragma unroll
    for (int d = 0; d < D_; d += 4) {
        float4 xv = *(const float4*)(xr + d);
        float4 yv = *(const float4*)(yr + d);
        d2 += sqdiff4(xv, yv);
    }
    float v = SCALE * expf(-GAMMA * d2);
    S0[idx] = v;
    C0[idx] = f2bf(v);
}

// f32-only variant (fallback path)
__global__ __launch_bounds__(256) void k_out0(const float* __restrict__ inps,
                                              const float* __restrict__ X,
                                              float* __restrict__ out0) {
    int idx = blockIdx.x * 256 + threadIdx.x;
    int l = idx & (L_ - 1);
    int m = (idx >> 4) & (M_ - 1);
    int b = idx >> 13;
    const float* xr = X + m * D_;
    const float* yr = inps + (b * L_ + l) * D_;
    float d2 = 0.f;
#pragma unroll
    for (int d = 0; d < D_; d += 4) {
        float4 xv = *(const float4*)(xr + d);
        float4 yv = *(const float4*)(yr + d);
        d2 += sqdiff4(xv, yv);
    }
    out0[idx] = SCALE * expf(-GAMMA * d2);
}

// ---- KY = RBF(nys_Y, nys_Y) * scale ----
__global__ __launch_bounds__(256) void k_ky(const float* __restrict__ Y,
                                            float* __restrict__ KY) {
    int idx = blockIdx.x * 256 + threadIdx.x;          // 512*512
    int j = idx & (M_ - 1);
    int i = idx >> 9;
    const float* yi = Y + i * D_;
    const float* yj = Y + j * D_;
    float d2 = 0.f;
#pragma unroll
    for (int d = 0; d < D_; d += 4) {
        float4 a = *(const float4*)(yi + d);
        float4 b = *(const float4*)(yj + d);
        d2 += sqdiff4(a, b);
    }
    KY[idx] = SCALE * expf(-GAMMA * d2);
}

// ---- W[m][a] = sum_j KY[m][j] * Y[j][a] ----
__global__ __launch_bounds__(256) void k_w(const float* __restrict__ KY,
                                           const float* __restrict__ Y,
                                           float* __restrict__ W) {
    int idx = blockIdx.x * 256 + threadIdx.x;          // 512*64
    int a = idx & (D_ - 1);
    int m = idx >> 6;
    float acc = 0.f;
    for (int j = 0; j < M_; ++j)
        acc = fmaf(KY[m * M_ + j], Y[j * D_ + a], acc);
    W[idx] = acc;
}

// ---- persistent cooperative scan: all 32 steps in one dispatch ----
// 256 blocks x 1024 thr (16 waves). Block owns 2 row-tiles (32 rows).
// wave w: tile = w&1, K-chunk kc = w>>1 (1024 wide = 32 MFMA k-slices).
// Step 1 reads f32 G, converts, writes packed Gp (own tiles only), MFMAs.
// Steps 2..32 read packed Gp. 8 K-partials LDS-reduced per tile
// (same summation structure as round 3 -> absmax ~0.0186).
// Gp fragment layout: short-index ((mt*256 + ks)*64 + lane)*8,
//   row = mt*16 + (lane&15), k = ks*32 + (lane>>4)*8 .. +8
__global__ __launch_bounds__(1024, 4) void k_scan(const float* __restrict__ G,
                                                  unsigned short* __restrict__ Gp,
                                                  unsigned short* __restrict__ Cb,
                                                  float* __restrict__ S) {
    const int bx   = blockIdx.x;            // 256 blocks
    const int w    = threadIdx.x >> 6;      // wave 0..15
    const int lane = threadIdx.x & 63;
    const int tile = w & 1;                 // 0/1
    const int kc   = w >> 1;                // K-chunk 0..7
    const int mt   = (bx << 1) + tile;      // row-tile 0..511
    const int r    = lane & 15;
    const int kk   = lane >> 4;

    unsigned short* gpw = Gp + ((size_t)(mt * 256 + kc * 32) * 64 + lane) * 8;
    const float*   gsrc = G + (size_t)(mt * 16 + r) * ML + kc * 1024 + kk * 8;

    __shared__ float red[2][8][256];
    cg::grid_group grid = cg::this_grid();

    for (int o = 1; o <= O_; ++o) {
        const unsigned short* bp = Cb + (size_t)(o - 1) * SLOT
                                      + (size_t)r * ML + kc * 1024 + kk * 8;
        f32x4 acc = {0.f, 0.f, 0.f, 0.f};
        if (o == 1) {
            // fused f32->bf16 cast + pack + MFMA
#pragma unroll 4
            for (int it = 0; it < 32; ++it) {
                float4 fa = *(const float4*)(gsrc + it * 32);
                float4 fb = *(const float4*)(gsrc + it * 32 + 4);
                union { short8 v; unsigned short u[8]; } oa;
                oa.u[0] = f2bf(fa.x); oa.u[1] = f2bf(fa.y);
                oa.u[2] = f2bf(fa.z); oa.u[3] = f2bf(fa.w);
                oa.u[4] = f2bf(fb.x); oa.u[5] = f2bf(fb.y);
                oa.u[6] = f2bf(fb.z); oa.u[7] = f2bf(fb.w);
                *(short8*)(gpw + (size_t)it * 512) = oa.v;
                short8 b = *(const short8*)(bp + it * 32);
                acc = __builtin_amdgcn_mfma_f32_16x16x32_bf16(oa.v, b, acc, 0, 0, 0);
            }
        } else {
#pragma unroll 8
            for (int it = 0; it < 32; ++it) {
                short8 a = *(const short8*)(gpw + (size_t)it * 512);
                short8 b = *(const short8*)(bp + it * 32);
                acc = __builtin_amdgcn_mfma_f32_16x16x32_bf16(a, b, acc, 0, 0, 0);
            }
        }

        // C/D layout: col = lane&15 (batch), row = (lane>>4)*4 + q
        const int rbase = kk << 2;
#pragma unroll
        for (int q = 0; q < 4; ++q)
            red[tile][kc][(rbase + q) * 16 + r] = acc[q];
        __syncthreads();

        if (threadIdx.x < 512) {
            const int t  = threadIdx.x;
            const int tl = t >> 8;
            const int t2 = t & 255;           // rr*16 + b
            const int b  = t2 & 15;
            const int i  = (bx << 5) + (tl << 4) + (t2 >> 4);
            float s = 0.f;
#pragma unroll
            for (int p = 0; p < 8; ++p) s += red[tl][p][t2];
            S [(size_t)o * SLOT + (size_t)b * ML + i] = s;
            Cb[(size_t)o * SLOT + (size_t)b * ML + i] = f2bf(s);
        }
        __threadfence();
        grid.sync();
    }
}

// ---- fallback f32 step (round-1 kernel) ----
__global__ __launch_bounds__(256) void k_step(const float* __restrict__ G,
                                              const float* __restrict__ carry,
                                              float* __restrict__ out) {
    const int i = blockIdx.x;
    const float* __restrict__ grow = G + (size_t)i * ML;
    float acc[B_];
#pragma unroll
    for (int b = 0; b < B_; ++b) acc[b] = 0.f;
    for (int j0 = threadIdx.x * 4; j0 < ML; j0 += 256 * 4) {
        float4 g = *(const float4*)(grow + j0);
#pragma unroll
        for (int b = 0; b < B_; ++b) {
            float4 c = *(const float4*)(carry + b * ML + j0);
            acc[b] = fmaf(g.x, c.x, fmaf(g.y, c.y, fmaf(g.z, c.z, fmaf(g.w, c.w, acc[b]))));
        }
    }
#pragma unroll
    for (int b = 0; b < B_; ++b) {
        float v = acc[b];
#pragma unroll
        for (int off = 32; off > 0; off >>= 1) v += __shfl_down(v, off, 64);
        acc[b] = v;
    }
    __shared__ float red2[4][B_];
    int lane = threadIdx.x & 63;
    int wv   = threadIdx.x >> 6;
    if (lane == 0) {
#pragma unroll
        for (int b = 0; b < B_; ++b) red2[wv][b] = acc[b];
    }
    __syncthreads();
    if (threadIdx.x < B_) {
        float v = red2[0][threadIdx.x] + red2[1][threadIdx.x] +
                  red2[2][threadIdx.x] + red2[3][threadIdx.x];
        out[threadIdx.x * ML + i] = v;
    }
}

// ---- final: out[((b*L+l)*O+o)*D+a] = sum_m W[m][a] * S[o+1][b][m*L+l] ----
__global__ __launch_bounds__(256) void k_final(const float* __restrict__ S,
                                               const float* __restrict__ W,
                                               float* __restrict__ out) {
    int t = blockIdx.x * 256 + threadIdx.x;            // 524288
    int a = t & (D_ - 1);
    int w = t >> 6;
    int o = w & (O_ - 1);
    int bl = w >> 5;
    int l = bl & (L_ - 1);
    int b = bl >> 4;
    const float* slot = S + (size_t)(o + 1) * SLOT + b * ML;
    float acc = 0.f;
    for (int m = 0; m < M_; ++m)
        acc = fmaf(slot[m * L_ + l], W[m * D_ + a], acc);
    out[t] = acc;
}

extern "C" void kernel_launch(void* const* d_in, const int* in_sizes, int n_in,
                              void* d_out, int out_size, void* d_ws, size_t ws_size,
                              hipStream_t stream) {
    const float* inps    = (const float*)d_in[0];   // [16,16,64]
    const float* nys_X   = (const float*)d_in[1];   // [512,64]
    const float* nys_Y   = (const float*)d_in[2];   // [512,64]
    const float* koopman = (const float*)d_in[3];   // [8192,8192]
    float* out = (float*)d_out;                     // [16,16,32,64]

    const size_t GB_BYTES  = (size_t)ML * ML * 2;          // 128 MB packed bf16
    const size_t S_BYTES   = (size_t)33 * SLOT * 4;        // 17.3 MB
    const size_t CB_BYTES  = (size_t)33 * SLOT * 2;        // 8.65 MB
    const size_t KY_BYTES  = (size_t)M_ * M_ * 4;
    const size_t W_BYTES   = (size_t)M_ * D_ * 4;
    const size_t NEED_FAST = GB_BYTES + S_BYTES + CB_BYTES + KY_BYTES + W_BYTES;

    if (ws_size >= NEED_FAST) {
        // ---------------- fast bf16-MFMA cooperative path ----------------
        unsigned short* Gp = (unsigned short*)d_ws;
        float*          S  = (float*)((char*)d_ws + GB_BYTES);
        unsigned short* Cb = (unsigned short*)((char*)S + S_BYTES);
        float*          KY = (float*)((char*)Cb + CB_BYTES);
        float*          W  = KY + M_ * M_;

        k_out0_dual<<<SLOT / 256, 256, 0, stream>>>(inps, nys_X, S, Cb);
        k_ky<<<(M_ * M_) / 256, 256, 0, stream>>>(nys_Y, KY);
        k_w<<<(M_ * D_) / 256, 256, 0, stream>>>(KY, nys_Y, W);

        {
            const float* Garg = koopman;
            unsigned short* Gparg = Gp;
            unsigned short* Cbarg = Cb;
            float* Sarg = S;
            void* args[] = { (void*)&Garg, (void*)&Gparg, (void*)&Cbarg, (void*)&Sarg };
            hipLaunchCooperativeKernel((void*)k_scan, dim3(256), dim3(1024),
                                       args, 0, stream);
        }

        k_final<<<(B_ * L_ * O_ * D_) / 256, 256, 0, stream>>>(S, W, out);
    } else {
        // ---------------- fallback f32 path (round-1) ----------------
        float* S  = (float*)d_ws;
        float* KY = S + (size_t)33 * SLOT;
        float* W  = KY + M_ * M_;

        k_out0<<<SLOT / 256, 256, 0, stream>>>(inps, nys_X, S);
        k_ky<<<(M_ * M_) / 256, 256, 0, stream>>>(nys_Y, KY);
        k_w<<<(M_ * D_) / 256, 256, 0, stream>>>(KY, nys_Y, W);
        for (int o = 1; o <= O_; ++o)
            k_step<<<ML, 256, 0, stream>>>(koopman, S + (size_t)(o - 1) * SLOT,
                                           S + (size_t)o * SLOT);
        k_final<<<(B_ * L_ * O_ * D_) / 256, 256, 0, stream>>>(S, W, out);
    }
}

// Round 7
// 1081.942 us; speedup vs baseline: 4.4541x; 4.4541x over previous
//
#include <hip/hip_runtime.h>
#include <hip/hip_bf16.h>

// Problem constants (KoopmanKernelSeq2Seq)
#define M_  512
#define L_  16
#define O_  32
#define D_  64
#define B_  16
#define ML  8192          // M_*L_
#define SLOT (B_*ML)      // 131072 elements per scan slot

typedef __attribute__((ext_vector_type(8))) short short8;
typedef __attribute__((ext_vector_type(4))) float f32x4;

static constexpr float GAMMA = 1.0f / 128.0f;          // 1/(2*D)
static constexpr float SCALE = 0.0441941738241592f;    // 512^-0.5

__device__ __forceinline__ float sqdiff4(const float4& x, const float4& y) {
    float dx = x.x - y.x, dy = x.y - y.y, dz = x.z - y.z, dw = x.w - y.w;
    return dx*dx + dy*dy + dz*dz + dw*dw;
}

__device__ __forceinline__ unsigned short f2bf(float x) {   // RNE f32->bf16
    unsigned u = __float_as_uint(x);
    u = (u + 0x7FFFu + ((u >> 16) & 1u)) >> 16;
    return (unsigned short)u;
}

// ---- out0: RBF(nys_X, inps), dual write f32 + bf16 ----
__global__ __launch_bounds__(256) void k_out0_dual(const float* __restrict__ inps,
                                                   const float* __restrict__ X,
                                                   float* __restrict__ S0,
                                                   unsigned short* __restrict__ C0) {
    int idx = blockIdx.x * 256 + threadIdx.x;          // B*M*L = 131072
    int l = idx & (L_ - 1);
    int m = (idx >> 4) & (M_ - 1);
    int b = idx >> 13;
    const float* xr = X + m * D_;
    const float* yr = inps + (b * L_ + l) * D_;
    float d2 = 0.f;
#pragma unroll
    for (int d = 0; d < D_; d += 4) {
        float4 xv = *(const float4*)(xr + d);
        float4 yv = *(const float4*)(yr + d);
        d2 += sqdiff4(xv, yv);
    }
    float v = SCALE * expf(-GAMMA * d2);
    S0[idx] = v;
    C0[idx] = f2bf(v);
}

// f32-only variant (fallback path)
__global__ __launch_bounds__(256) void k_out0(const float* __restrict__ inps,
                                              const float* __restrict__ X,
                                              float* __restrict__ out0) {
    int idx = blockIdx.x * 256 + threadIdx.x;
    int l = idx & (L_ - 1);
    int m = (idx >> 4) & (M_ - 1);
    int b = idx >> 13;
    const float* xr = X + m * D_;
    const float* yr = inps + (b * L_ + l) * D_;
    float d2 = 0.f;
#pragma unroll
    for (int d = 0; d < D_; d += 4) {
        float4 xv = *(const float4*)(xr + d);
        float4 yv = *(const float4*)(yr + d);
        d2 += sqdiff4(xv, yv);
    }
    out0[idx] = SCALE * expf(-GAMMA * d2);
}

// ---- KY = RBF(nys_Y, nys_Y) * scale ----
__global__ __launch_bounds__(256) void k_ky(const float* __restrict__ Y,
                                            float* __restrict__ KY) {
    int idx = blockIdx.x * 256 + threadIdx.x;          // 512*512
    int j = idx & (M_ - 1);
    int i = idx >> 9;
    const float* yi = Y + i * D_;
    const float* yj = Y + j * D_;
    float d2 = 0.f;
#pragma unroll
    for (int d = 0; d < D_; d += 4) {
        float4 a = *(const float4*)(yi + d);
        float4 b = *(const float4*)(yj + d);
        d2 += sqdiff4(a, b);
    }
    KY[idx] = SCALE * expf(-GAMMA * d2);
}

// ---- W[m][a] = sum_j KY[m][j] * Y[j][a] ----
__global__ __launch_bounds__(256) void k_w(const float* __restrict__ KY,
                                           const float* __restrict__ Y,
                                           float* __restrict__ W) {
    int idx = blockIdx.x * 256 + threadIdx.x;          // 512*64
    int a = idx & (D_ - 1);
    int m = idx >> 6;
    float acc = 0.f;
    for (int j = 0; j < M_; ++j)
        acc = fmaf(KY[m * M_ + j], Y[j * D_ + a], acc);
    W[idx] = acc;
}

// Gp fragment layout: short-index ((mt*256 + ks)*64 + lane)*8
//   row = mt*16 + (lane&15), k = ks*32 + (lane>>4)*8 .. +8
//   -> one wave A-load = 1KB contiguous.
// nt policy: K-chunks w<4 (cols [0,4096)) use non-temporal (no-allocate)
// loads/stores -> stream from HBM; w>=4 stays L3-resident. The two memory
// paths overlap if the MALL honors no-allocate.

// ---- step 1: fused f32->bf16 cast + pack + MFMA ----
// 256 blocks x 512 thr (8 waves). Block owns rows [bx*32, bx*32+32) as two
// 16-row tiles; wave w = K-chunk w*1024..+1024; both tiles share B-frag.
__global__ __launch_bounds__(512, 2) void k_step_first(const float* __restrict__ G,
                                                       unsigned short* __restrict__ Gp,
                                                       const unsigned short* __restrict__ Cin,
                                                       float* __restrict__ Sout,
                                                       unsigned short* __restrict__ Cout) {
    const int bx   = blockIdx.x;
    const int w    = threadIdx.x >> 6;
    const int lane = threadIdx.x & 63;
    const int r    = lane & 15;
    const int kk   = lane >> 4;
    const size_t kbase = (size_t)w * 1024 + kk * 8;
    const int mt0 = bx * 2, mt1 = bx * 2 + 1;

    const float* g0 = G + (size_t)(mt0 * 16 + r) * ML + kbase;
    const float* g1 = G + (size_t)(mt1 * 16 + r) * ML + kbase;
    unsigned short* gp0 = Gp + ((size_t)(mt0 * 256 + w * 32) * 64 + lane) * 8;
    unsigned short* gp1 = Gp + ((size_t)(mt1 * 256 + w * 32) * 64 + lane) * 8;
    const unsigned short* bp = Cin + (size_t)r * ML + kbase;

    const bool nt = (w < 4);
    f32x4 acc0 = {0.f, 0.f, 0.f, 0.f};
    f32x4 acc1 = {0.f, 0.f, 0.f, 0.f};
#pragma unroll 2
    for (int it = 0; it < 32; ++it) {
        short8 bv = *(const short8*)(bp + it * 32);
        // tile 0
        f32x4 fa = __builtin_nontemporal_load((const f32x4*)(g0 + it * 32));
        f32x4 fb = __builtin_nontemporal_load((const f32x4*)(g0 + it * 32 + 4));
        union { short8 v; unsigned short u[8]; } oa;
        oa.u[0] = f2bf(fa.x); oa.u[1] = f2bf(fa.y); oa.u[2] = f2bf(fa.z); oa.u[3] = f2bf(fa.w);
        oa.u[4] = f2bf(fb.x); oa.u[5] = f2bf(fb.y); oa.u[6] = f2bf(fb.z); oa.u[7] = f2bf(fb.w);
        if (nt) __builtin_nontemporal_store(oa.v, (short8*)(gp0 + (size_t)it * 512));
        else    *(short8*)(gp0 + (size_t)it * 512) = oa.v;
        acc0 = __builtin_amdgcn_mfma_f32_16x16x32_bf16(oa.v, bv, acc0, 0, 0, 0);
        // tile 1
        f32x4 fc = __builtin_nontemporal_load((const f32x4*)(g1 + it * 32));
        f32x4 fd = __builtin_nontemporal_load((const f32x4*)(g1 + it * 32 + 4));
        union { short8 v; unsigned short u[8]; } ob;
        ob.u[0] = f2bf(fc.x); ob.u[1] = f2bf(fc.y); ob.u[2] = f2bf(fc.z); ob.u[3] = f2bf(fc.w);
        ob.u[4] = f2bf(fd.x); ob.u[5] = f2bf(fd.y); ob.u[6] = f2bf(fd.z); ob.u[7] = f2bf(fd.w);
        if (nt) __builtin_nontemporal_store(ob.v, (short8*)(gp1 + (size_t)it * 512));
        else    *(short8*)(gp1 + (size_t)it * 512) = ob.v;
        acc1 = __builtin_amdgcn_mfma_f32_16x16x32_bf16(ob.v, bv, acc1, 0, 0, 0);
    }

    // C/D layout: col = lane&15 (batch), row = (lane>>4)*4 + q
    __shared__ float red[2][8][256];
    const int rbase = kk << 2;
#pragma unroll
    for (int q = 0; q < 4; ++q) {
        red[0][w][(rbase + q) * 16 + r] = acc0[q];
        red[1][w][(rbase + q) * 16 + r] = acc1[q];
    }
    __syncthreads();

    const int t = threadIdx.x;          // 512 = 2 tiles * 256
    const int tl = t >> 8;
    const int t2 = t & 255;             // rr*16 + b
    float s = 0.f;
#pragma unroll
    for (int p = 0; p < 8; ++p) s += red[tl][p][t2];
    const int b = t2 & 15;
    const int i = (bx << 5) + (tl << 4) + (t2 >> 4);
    Sout[(size_t)b * ML + i] = s;
    Cout[(size_t)b * ML + i] = f2bf(s);
}

// ---- steps 2..32: packed-G MFMA step ----
template<bool NT>
__device__ __forceinline__ void step_loop(const unsigned short* ap0,
                                          const unsigned short* ap1,
                                          const unsigned short* bp,
                                          f32x4& acc0, f32x4& acc1) {
#pragma unroll 4
    for (int it = 0; it < 32; ++it) {
        short8 bv = *(const short8*)(bp + it * 32);
        short8 a0, a1;
        if constexpr (NT) {
            a0 = __builtin_nontemporal_load((const short8*)(ap0 + (size_t)it * 512));
            a1 = __builtin_nontemporal_load((const short8*)(ap1 + (size_t)it * 512));
        } else {
            a0 = *(const short8*)(ap0 + (size_t)it * 512);
            a1 = *(const short8*)(ap1 + (size_t)it * 512);
        }
        acc0 = __builtin_amdgcn_mfma_f32_16x16x32_bf16(a0, bv, acc0, 0, 0, 0);
        acc1 = __builtin_amdgcn_mfma_f32_16x16x32_bf16(a1, bv, acc1, 0, 0, 0);
    }
}

__global__ __launch_bounds__(512, 4) void k_step_next(const unsigned short* __restrict__ Gp,
                                                      const unsigned short* __restrict__ Cin,
                                                      float* __restrict__ Sout,
                                                      unsigned short* __restrict__ Cout) {
    const int bx   = blockIdx.x;
    const int w    = threadIdx.x >> 6;
    const int lane = threadIdx.x & 63;
    const int r    = lane & 15;
    const int kk   = lane >> 4;
    const size_t kbase = (size_t)w * 1024 + kk * 8;
    const int mt0 = bx * 2, mt1 = bx * 2 + 1;

    const unsigned short* ap0 = Gp + ((size_t)(mt0 * 256 + w * 32) * 64 + lane) * 8;
    const unsigned short* ap1 = Gp + ((size_t)(mt1 * 256 + w * 32) * 64 + lane) * 8;
    const unsigned short* bp  = Cin + (size_t)r * ML + kbase;

    f32x4 acc0 = {0.f, 0.f, 0.f, 0.f};
    f32x4 acc1 = {0.f, 0.f, 0.f, 0.f};
    if (w < 4) step_loop<true >(ap0, ap1, bp, acc0, acc1);
    else       step_loop<false>(ap0, ap1, bp, acc0, acc1);

    __shared__ float red[2][8][256];
    const int rbase = kk << 2;
#pragma unroll
    for (int q = 0; q < 4; ++q) {
        red[0][w][(rbase + q) * 16 + r] = acc0[q];
        red[1][w][(rbase + q) * 16 + r] = acc1[q];
    }
    __syncthreads();

    const int t = threadIdx.x;
    const int tl = t >> 8;
    const int t2 = t & 255;
    float s = 0.f;
#pragma unroll
    for (int p = 0; p < 8; ++p) s += red[tl][p][t2];
    const int b = t2 & 15;
    const int i = (bx << 5) + (tl << 4) + (t2 >> 4);
    Sout[(size_t)b * ML + i] = s;
    Cout[(size_t)b * ML + i] = f2bf(s);
}

// ---- fallback f32 step (round-1 kernel) ----
__global__ __launch_bounds__(256) void k_step(const float* __restrict__ G,
                                              const float* __restrict__ carry,
                                              float* __restrict__ out) {
    const int i = blockIdx.x;
    const float* __restrict__ grow = G + (size_t)i * ML;
    float acc[B_];
#pragma unroll
    for (int b = 0; b < B_; ++b) acc[b] = 0.f;
    for (int j0 = threadIdx.x * 4; j0 < ML; j0 += 256 * 4) {
        float4 g = *(const float4*)(grow + j0);
#pragma unroll
        for (int b = 0; b < B_; ++b) {
            float4 c = *(const float4*)(carry + b * ML + j0);
            acc[b] = fmaf(g.x, c.x, fmaf(g.y, c.y, fmaf(g.z, c.z, fmaf(g.w, c.w, acc[b]))));
        }
    }
#pragma unroll
    for (int b = 0; b < B_; ++b) {
        float v = acc[b];
#pragma unroll
        for (int off = 32; off > 0; off >>= 1) v += __shfl_down(v, off, 64);
        acc[b] = v;
    }
    __shared__ float red2[4][B_];
    int lane = threadIdx.x & 63;
    int wv   = threadIdx.x >> 6;
    if (lane == 0) {
#pragma unroll
        for (int b = 0; b < B_; ++b) red2[wv][b] = acc[b];
    }
    __syncthreads();
    if (threadIdx.x < B_) {
        float v = red2[0][threadIdx.x] + red2[1][threadIdx.x] +
                  red2[2][threadIdx.x] + red2[3][threadIdx.x];
        out[threadIdx.x * ML + i] = v;
    }
}

// ---- final: out[((b*L+l)*O+o)*D+a] = sum_m W[m][a] * S[o+1][b][m*L+l] ----
__global__ __launch_bounds__(256) void k_final(const float* __restrict__ S,
                                               const float* __restrict__ W,
                                               float* __restrict__ out) {
    int t = blockIdx.x * 256 + threadIdx.x;            // 524288
    int a = t & (D_ - 1);
    int w = t >> 6;
    int o = w & (O_ - 1);
    int bl = w >> 5;
    int l = bl & (L_ - 1);
    int b = bl >> 4;
    const float* slot = S + (size_t)(o + 1) * SLOT + b * ML;
    float acc = 0.f;
    for (int m = 0; m < M_; ++m)
        acc = fmaf(slot[m * L_ + l], W[m * D_ + a], acc);
    out[t] = acc;
}

extern "C" void kernel_launch(void* const* d_in, const int* in_sizes, int n_in,
                              void* d_out, int out_size, void* d_ws, size_t ws_size,
                              hipStream_t stream) {
    const float* inps    = (const float*)d_in[0];   // [16,16,64]
    const float* nys_X   = (const float*)d_in[1];   // [512,64]
    const float* nys_Y   = (const float*)d_in[2];   // [512,64]
    const float* koopman = (const float*)d_in[3];   // [8192,8192]
    float* out = (float*)d_out;                     // [16,16,32,64]

    const size_t GB_BYTES  = (size_t)ML * ML * 2;          // 128 MB packed bf16
    const size_t S_BYTES   = (size_t)33 * SLOT * 4;        // 17.3 MB
    const size_t CB_BYTES  = (size_t)33 * SLOT * 2;        // 8.65 MB
    const size_t KY_BYTES  = (size_t)M_ * M_ * 4;
    const size_t W_BYTES   = (size_t)M_ * D_ * 4;
    const size_t NEED_FAST = GB_BYTES + S_BYTES + CB_BYTES + KY_BYTES + W_BYTES;

    if (ws_size >= NEED_FAST) {
        // ---------------- fast bf16-MFMA path ----------------
        unsigned short* Gp = (unsigned short*)d_ws;
        float*          S  = (float*)((char*)d_ws + GB_BYTES);
        unsigned short* Cb = (unsigned short*)((char*)S + S_BYTES);
        float*          KY = (float*)((char*)Cb + CB_BYTES);
        float*          W  = KY + M_ * M_;

        k_out0_dual<<<SLOT / 256, 256, 0, stream>>>(inps, nys_X, S, Cb);
        k_ky<<<(M_ * M_) / 256, 256, 0, stream>>>(nys_Y, KY);
        k_w<<<(M_ * D_) / 256, 256, 0, stream>>>(KY, nys_Y, W);

        k_step_first<<<256, 512, 0, stream>>>(koopman, Gp, Cb,
                                              S + (size_t)1 * SLOT,
                                              Cb + (size_t)1 * SLOT);
        for (int o = 2; o <= O_; ++o) {
            k_step_next<<<256, 512, 0, stream>>>(Gp,
                                                 Cb + (size_t)(o - 1) * SLOT,
                                                 S + (size_t)o * SLOT,
                                                 Cb + (size_t)o * SLOT);
        }
        k_final<<<(B_ * L_ * O_ * D_) / 256, 256, 0, stream>>>(S, W, out);
    } else {
        // ---------------- fallback f32 path (round-1) ----------------
        float* S  = (float*)d_ws;
        float* KY = S + (size_t)33 * SLOT;
        float* W  = KY + M_ * M_;

        k_out0<<<SLOT / 256, 256, 0, stream>>>(inps, nys_X, S);
        k_ky<<<(M_ * M_) / 256, 256, 0, stream>>>(nys_Y, KY);
        k_w<<<(M_ * D_) / 256, 256, 0, stream>>>(KY, nys_Y, W);
        for (int o = 1; o <= O_; ++o)
            k_step<<<ML, 256, 0, stream>>>(koopman, S + (size_t)(o - 1) * SLOT,
                                           S + (size_t)o * SLOT);
        k_final<<<(B_ * L_ * O_ * D_) / 256, 256, 0, stream>>>(S, W, out);
    }
}

// Round 9
// 1075.940 us; speedup vs baseline: 4.4790x; 1.0056x over previous
//
#include <hip/hip_runtime.h>
#include <hip/hip_bf16.h>

// Problem constants (KoopmanKernelSeq2Seq)
#define M_  512
#define L_  16
#define O_  32
#define D_  64
#define B_  16
#define ML  8192          // M_*L_
#define SLOT (B_*ML)      // 131072 elements per scan slot

typedef __attribute__((ext_vector_type(8))) short short8;
typedef __attribute__((ext_vector_type(4))) float f32x4;

static constexpr float GAMMA = 1.0f / 128.0f;          // 1/(2*D)
static constexpr float SCALE = 0.0441941738241592f;    // 512^-0.5

__device__ __forceinline__ float sqdiff4(const float4& x, const float4& y) {
    float dx = x.x - y.x, dy = x.y - y.y, dz = x.z - y.z, dw = x.w - y.w;
    return dx*dx + dy*dy + dz*dz + dw*dw;
}

__device__ __forceinline__ unsigned short f2bf(float x) {   // RNE f32->bf16
    unsigned u = __float_as_uint(x);
    u = (u + 0x7FFFu + ((u >> 16) & 1u)) >> 16;
    return (unsigned short)u;
}

// ---- out0: RBF(nys_X, inps), dual write f32 + bf16 ----
__global__ __launch_bounds__(256) void k_out0_dual(const float* __restrict__ inps,
                                                   const float* __restrict__ X,
                                                   float* __restrict__ S0,
                                                   unsigned short* __restrict__ C0) {
    int idx = blockIdx.x * 256 + threadIdx.x;          // B*M*L = 131072
    int l = idx & (L_ - 1);
    int m = (idx >> 4) & (M_ - 1);
    int b = idx >> 13;
    const float* xr = X + m * D_;
    const float* yr = inps + (b * L_ + l) * D_;
    float d2 = 0.f;
#pragma unroll
    for (int d = 0; d < D_; d += 4) {
        float4 xv = *(const float4*)(xr + d);
        float4 yv = *(const float4*)(yr + d);
        d2 += sqdiff4(xv, yv);
    }
    float v = SCALE * expf(-GAMMA * d2);
    S0[idx] = v;
    C0[idx] = f2bf(v);
}

// f32-only variant (fallback path)
__global__ __launch_bounds__(256) void k_out0(const float* __restrict__ inps,
                                              const float* __restrict__ X,
                                              float* __restrict__ out0) {
    int idx = blockIdx.x * 256 + threadIdx.x;
    int l = idx & (L_ - 1);
    int m = (idx >> 4) & (M_ - 1);
    int b = idx >> 13;
    const float* xr = X + m * D_;
    const float* yr = inps + (b * L_ + l) * D_;
    float d2 = 0.f;
#pragma unroll
    for (int d = 0; d < D_; d += 4) {
        float4 xv = *(const float4*)(xr + d);
        float4 yv = *(const float4*)(yr + d);
        d2 += sqdiff4(xv, yv);
    }
    out0[idx] = SCALE * expf(-GAMMA * d2);
}

// ---- KY = RBF(nys_Y, nys_Y) * scale ----
__global__ __launch_bounds__(256) void k_ky(const float* __restrict__ Y,
                                            float* __restrict__ KY) {
    int idx = blockIdx.x * 256 + threadIdx.x;          // 512*512
    int j = idx & (M_ - 1);
    int i = idx >> 9;
    const float* yi = Y + i * D_;
    const float* yj = Y + j * D_;
    float d2 = 0.f;
#pragma unroll
    for (int d = 0; d < D_; d += 4) {
        float4 a = *(const float4*)(yi + d);
        float4 b = *(const float4*)(yj + d);
        d2 += sqdiff4(a, b);
    }
    KY[idx] = SCALE * expf(-GAMMA * d2);
}

// ---- W[m][a] = sum_j KY[m][j] * Y[j][a] ----
__global__ __launch_bounds__(256) void k_w(const float* __restrict__ KY,
                                           const float* __restrict__ Y,
                                           float* __restrict__ W) {
    int idx = blockIdx.x * 256 + threadIdx.x;          // 512*64
    int a = idx & (D_ - 1);
    int m = idx >> 6;
    float acc = 0.f;
    for (int j = 0; j < M_; ++j)
        acc = fmaf(KY[m * M_ + j], Y[j * D_ + a], acc);
    W[idx] = acc;
}

// Gp fragment layout: short-index ((mt*256 + ks)*64 + lane)*8
//   row = mt*16 + (lane&15), k = ks*32 + (lane>>4)*8 .. +8
//   -> one wave A-load = 1KB contiguous.

// ---- step 1: fused f32->bf16 cast + pack + MFMA (no nt — r7 post-mortem:
// nt split cost ~+3us/step; all-cached is the fastest measured path) ----
// 256 blocks x 512 thr (8 waves). Block owns rows [bx*32,+32) as two 16-row
// tiles; wave w = K-chunk w*1024..+1024; both tiles share the B fragment.
__global__ __launch_bounds__(512, 2) void k_step_first(const float* __restrict__ G,
                                                       unsigned short* __restrict__ Gp,
                                                       const unsigned short* __restrict__ Cin,
                                                       float* __restrict__ Sout,
                                                       unsigned short* __restrict__ Cout) {
    const int bx   = blockIdx.x;
    const int w    = threadIdx.x >> 6;
    const int lane = threadIdx.x & 63;
    const int r    = lane & 15;
    const int kk   = lane >> 4;
    const size_t kbase = (size_t)w * 1024 + kk * 8;
    const int mt0 = bx * 2, mt1 = bx * 2 + 1;

    const float* g0 = G + (size_t)(mt0 * 16 + r) * ML + kbase;
    const float* g1 = G + (size_t)(mt1 * 16 + r) * ML + kbase;
    unsigned short* gp0 = Gp + ((size_t)(mt0 * 256 + w * 32) * 64 + lane) * 8;
    unsigned short* gp1 = Gp + ((size_t)(mt1 * 256 + w * 32) * 64 + lane) * 8;
    const unsigned short* bp = Cin + (size_t)r * ML + kbase;

    f32x4 acc0 = {0.f, 0.f, 0.f, 0.f};
    f32x4 acc1 = {0.f, 0.f, 0.f, 0.f};
#pragma unroll 2
    for (int it = 0; it < 32; ++it) {
        short8 bv = *(const short8*)(bp + it * 32);
        // tile 0
        f32x4 fa = *(const f32x4*)(g0 + it * 32);
        f32x4 fb = *(const f32x4*)(g0 + it * 32 + 4);
        union { short8 v; unsigned short u[8]; } oa;
        oa.u[0] = f2bf(fa.x); oa.u[1] = f2bf(fa.y); oa.u[2] = f2bf(fa.z); oa.u[3] = f2bf(fa.w);
        oa.u[4] = f2bf(fb.x); oa.u[5] = f2bf(fb.y); oa.u[6] = f2bf(fb.z); oa.u[7] = f2bf(fb.w);
        *(short8*)(gp0 + (size_t)it * 512) = oa.v;
        acc0 = __builtin_amdgcn_mfma_f32_16x16x32_bf16(oa.v, bv, acc0, 0, 0, 0);
        // tile 1
        f32x4 fc = *(const f32x4*)(g1 + it * 32);
        f32x4 fd = *(const f32x4*)(g1 + it * 32 + 4);
        union { short8 v; unsigned short u[8]; } ob;
        ob.u[0] = f2bf(fc.x); ob.u[1] = f2bf(fc.y); ob.u[2] = f2bf(fc.z); ob.u[3] = f2bf(fc.w);
        ob.u[4] = f2bf(fd.x); ob.u[5] = f2bf(fd.y); ob.u[6] = f2bf(fd.z); ob.u[7] = f2bf(fd.w);
        *(short8*)(gp1 + (size_t)it * 512) = ob.v;
        acc1 = __builtin_amdgcn_mfma_f32_16x16x32_bf16(ob.v, bv, acc1, 0, 0, 0);
    }

    // C/D layout: col = lane&15 (batch), row = (lane>>4)*4 + q
    __shared__ float red[2][8][256];
    const int rbase = kk << 2;
#pragma unroll
    for (int q = 0; q < 4; ++q) {
        red[0][w][(rbase + q) * 16 + r] = acc0[q];
        red[1][w][(rbase + q) * 16 + r] = acc1[q];
    }
    __syncthreads();

    const int t = threadIdx.x;          // 512 = 2 tiles * 256
    const int tl = t >> 8;
    const int t2 = t & 255;             // rr*16 + b
    float s = 0.f;
#pragma unroll
    for (int p = 0; p < 8; ++p) s += red[tl][p][t2];
    const int b = t2 & 15;
    const int i = (bx << 5) + (tl << 4) + (t2 >> 4);
    Sout[(size_t)b * ML + i] = s;
    Cout[(size_t)b * ML + i] = f2bf(s);
}

// ---- steps 2..32: packed-G MFMA step (all cached) ----
__global__ __launch_bounds__(512, 4) void k_step_next(const unsigned short* __restrict__ Gp,
                                                      const unsigned short* __restrict__ Cin,
                                                      float* __restrict__ Sout,
                                                      unsigned short* __restrict__ Cout) {
    const int bx   = blockIdx.x;
    const int w    = threadIdx.x >> 6;
    const int lane = threadIdx.x & 63;
    const int r    = lane & 15;
    const int kk   = lane >> 4;
    const size_t kbase = (size_t)w * 1024 + kk * 8;
    const int mt0 = bx * 2, mt1 = bx * 2 + 1;

    const unsigned short* ap0 = Gp + ((size_t)(mt0 * 256 + w * 32) * 64 + lane) * 8;
    const unsigned short* ap1 = Gp + ((size_t)(mt1 * 256 + w * 32) * 64 + lane) * 8;
    const unsigned short* bp  = Cin + (size_t)r * ML + kbase;

    f32x4 acc0 = {0.f, 0.f, 0.f, 0.f};
    f32x4 acc1 = {0.f, 0.f, 0.f, 0.f};
#pragma unroll 4
    for (int it = 0; it < 32; ++it) {
        short8 bv = *(const short8*)(bp + it * 32);
        short8 a0 = *(const short8*)(ap0 + (size_t)it * 512);
        short8 a1 = *(const short8*)(ap1 + (size_t)it * 512);
        acc0 = __builtin_amdgcn_mfma_f32_16x16x32_bf16(a0, bv, acc0, 0, 0, 0);
        acc1 = __builtin_amdgcn_mfma_f32_16x16x32_bf16(a1, bv, acc1, 0, 0, 0);
    }

    __shared__ float red[2][8][256];
    const int rbase = kk << 2;
#pragma unroll
    for (int q = 0; q < 4; ++q) {
        red[0][w][(rbase + q) * 16 + r] = acc0[q];
        red[1][w][(rbase + q) * 16 + r] = acc1[q];
    }
    __syncthreads();

    const int t = threadIdx.x;
    const int tl = t >> 8;
    const int t2 = t & 255;
    float s = 0.f;
#pragma unroll
    for (int p = 0; p < 8; ++p) s += red[tl][p][t2];
    const int b = t2 & 15;
    const int i = (bx << 5) + (tl << 4) + (t2 >> 4);
    Sout[(size_t)b * ML + i] = s;
    Cout[(size_t)b * ML + i] = f2bf(s);
}

// ---- fallback f32 step (round-1 kernel) ----
__global__ __launch_bounds__(256) void k_step(const float* __restrict__ G,
                                              const float* __restrict__ carry,
                                              float* __restrict__ out) {
    const int i = blockIdx.x;
    const float* __restrict__ grow = G + (size_t)i * ML;
    float acc[B_];
#pragma unroll
    for (int b = 0; b < B_; ++b) acc[b] = 0.f;
    for (int j0 = threadIdx.x * 4; j0 < ML; j0 += 256 * 4) {
        float4 g = *(const float4*)(grow + j0);
#pragma unroll
        for (int b = 0; b < B_; ++b) {
            float4 c = *(const float4*)(carry + b * ML + j0);
            acc[b] = fmaf(g.x, c.x, fmaf(g.y, c.y, fmaf(g.z, c.z, fmaf(g.w, c.w, acc[b]))));
        }
    }
#pragma unroll
    for (int b = 0; b < B_; ++b) {
        float v = acc[b];
#pragma unroll
        for (int off = 32; off > 0; off >>= 1) v += __shfl_down(v, off, 64);
        acc[b] = v;
    }
    __shared__ float red2[4][B_];
    int lane = threadIdx.x & 63;
    int wv   = threadIdx.x >> 6;
    if (lane == 0) {
#pragma unroll
        for (int b = 0; b < B_; ++b) red2[wv][b] = acc[b];
    }
    __syncthreads();
    if (threadIdx.x < B_) {
        float v = red2[0][threadIdx.x] + red2[1][threadIdx.x] +
                  red2[2][threadIdx.x] + red2[3][threadIdx.x];
        out[threadIdx.x * ML + i] = v;
    }
}

// ---- final, W-reuse structure ----
// Block = (b*16 + l), 256 threads: a = t&63, og = t>>6 (wave id).
// Thread accumulates 8 o's (o = og + 4*i). W row loads are coalesced and
// read once per block (32MB total vs 1GB in the old broadcast version);
// S loads are wave-uniform scalars. f32 math identical to reference order.
__global__ __launch_bounds__(256) void k_final2(const float* __restrict__ S,
                                                const float* __restrict__ W,
                                                float* __restrict__ out) {
    const int bid = blockIdx.x;             // 256 = B*L
    const int b = bid >> 4;
    const int l = bid & 15;
    const int a  = threadIdx.x & 63;
    const int og = threadIdx.x >> 6;        // 0..3

    float acc[8];
#pragma unroll
    for (int i = 0; i < 8; ++i) acc[i] = 0.f;

    const float* sbase = S + (size_t)b * ML + l;
    for (int m = 0; m < M_; ++m) {
        float wa = W[m * D_ + a];
#pragma unroll
        for (int i = 0; i < 8; ++i) {
            int o = og + 4 * i;             // 0..31
            float sv = sbase[(size_t)(o + 1) * SLOT + m * L_];
            acc[i] = fmaf(sv, wa, acc[i]);
        }
    }
#pragma unroll
    for (int i = 0; i < 8; ++i) {
        int o = og + 4 * i;
        out[((size_t)bid * O_ + o) * D_ + a] = acc[i];
    }
}

extern "C" void kernel_launch(void* const* d_in, const int* in_sizes, int n_in,
                              void* d_out, int out_size, void* d_ws, size_t ws_size,
                              hipStream_t stream) {
    const float* inps    = (const float*)d_in[0];   // [16,16,64]
    const float* nys_X   = (const float*)d_in[1];   // [512,64]
    const float* nys_Y   = (const float*)d_in[2];   // [512,64]
    const float* koopman = (const float*)d_in[3];   // [8192,8192]
    float* out = (float*)d_out;                     // [16,16,32,64]

    const size_t GB_BYTES  = (size_t)ML * ML * 2;          // 128 MB packed bf16
    const size_t S_BYTES   = (size_t)33 * SLOT * 4;        // 17.3 MB
    const size_t CB_BYTES  = (size_t)33 * SLOT * 2;        // 8.65 MB
    const size_t KY_BYTES  = (size_t)M_ * M_ * 4;
    const size_t W_BYTES   = (size_t)M_ * D_ * 4;
    const size_t NEED_FAST = GB_BYTES + S_BYTES + CB_BYTES + KY_BYTES + W_BYTES;

    if (ws_size >= NEED_FAST) {
        // ---------------- fast bf16-MFMA path ----------------
        unsigned short* Gp = (unsigned short*)d_ws;
        float*          S  = (float*)((char*)d_ws + GB_BYTES);
        unsigned short* Cb = (unsigned short*)((char*)S + S_BYTES);
        float*          KY = (float*)((char*)Cb + CB_BYTES);
        float*          W  = KY + M_ * M_;

        k_out0_dual<<<SLOT / 256, 256, 0, stream>>>(inps, nys_X, S, Cb);
        k_ky<<<(M_ * M_) / 256, 256, 0, stream>>>(nys_Y, KY);
        k_w<<<(M_ * D_) / 256, 256, 0, stream>>>(KY, nys_Y, W);

        k_step_first<<<256, 512, 0, stream>>>(koopman, Gp, Cb,
                                              S + (size_t)1 * SLOT,
                                              Cb + (size_t)1 * SLOT);
        for (int o = 2; o <= O_; ++o) {
            k_step_next<<<256, 512, 0, stream>>>(Gp,
                                                 Cb + (size_t)(o - 1) * SLOT,
                                                 S + (size_t)o * SLOT,
                                                 Cb + (size_t)o * SLOT);
        }
        k_final2<<<B_ * L_, 256, 0, stream>>>(S, W, out);
    } else {
        // ---------------- fallback f32 path (round-1) ----------------
        float* S  = (float*)d_ws;
        float* KY = S + (size_t)33 * SLOT;
        float* W  = KY + M_ * M_;

        k_out0<<<SLOT / 256, 256, 0, stream>>>(inps, nys_X, S);
        k_ky<<<(M_ * M_) / 256, 256, 0, stream>>>(nys_Y, KY);
        k_w<<<(M_ * D_) / 256, 256, 0, stream>>>(KY, nys_Y, W);
        for (int o = 1; o <= O_; ++o)
            k_step<<<ML, 256, 0, stream>>>(koopman, S + (size_t)(o - 1) * SLOT,
                                           S + (size_t)o * SLOT);
        k_final2<<<B_ * L_, 256, 0, stream>>>(S, W, out);
    }
}